// Round 11
// baseline (50.390 us; speedup 1.0000x reference)
//
#include <hip/hip_runtime.h>
#include <math.h>

typedef __attribute__((ext_vector_type(8))) short bf16x8;
typedef __attribute__((ext_vector_type(4))) float f32x4;

constexpr int D   = 1280;  // input dim
constexpr int H   = 64;    // hidden
constexpr int BM  = 128;   // rows per block
constexpr int NT  = 512;   // threads per block (8 waves)
constexpr int KC  = 64;    // K chunk
constexpr int SW  = KC + 8;   // W-tile LDS row stride in bf16 (verified r2 layout)
constexpr int HSS = H + 1;

union FragU { bf16x8 v; unsigned int u[4]; };

// truncation split of two f32 into packed bf16 hi pair + bf16 lo pair
__device__ __forceinline__ unsigned int pack_split(float f0, float f1, unsigned int& lo) {
    unsigned int u0 = __float_as_uint(f0), u1 = __float_as_uint(f1);
    unsigned int h0 = u0 & 0xFFFF0000u,    h1 = u1 & 0xFFFF0000u;
    float l0 = f0 - __uint_as_float(h0);
    float l1 = f1 - __uint_as_float(h1);
    lo = (__float_as_uint(l1) & 0xFFFF0000u) | (__float_as_uint(l0) >> 16);
    return h1 | (u0 >> 16);
}

// ---------------- quantum gates: 4-qubit statevector, bit weight BW ----------
template<int BW>
__device__ __forceinline__ void ry_gate(float re[16], float im[16], float theta) {
    float sn, cs;
    sincosf(0.5f * theta, &sn, &cs);
#pragma unroll
    for (int s0 = 0; s0 < 16; ++s0) {
        if (s0 & BW) continue;
        const int s1 = s0 | BW;
        float r0 = re[s0], i0 = im[s0], r1 = re[s1], i1 = im[s1];
        re[s0] = cs * r0 - sn * r1;  im[s0] = cs * i0 - sn * i1;
        re[s1] = sn * r0 + cs * r1;  im[s1] = sn * i0 + cs * i1;
    }
}

template<int BW>
__device__ __forceinline__ void rz_gate(float re[16], float im[16], float theta) {
    float sn, cs;
    sincosf(0.5f * theta, &sn, &cs);
#pragma unroll
    for (int s0 = 0; s0 < 16; ++s0) {
        if (s0 & BW) continue;
        const int s1 = s0 | BW;
        float r0 = re[s0], i0 = im[s0], r1 = re[s1], i1 = im[s1];
        re[s0] = cs * r0 + sn * i0;  im[s0] = cs * i0 - sn * r0;
        re[s1] = cs * r1 - sn * i1;  im[s1] = cs * i1 + sn * r1;
    }
}

template<int BWC, int BWT>
__device__ __forceinline__ void cnot_gate(float re[16], float im[16]) {
#pragma unroll
    for (int s = 0; s < 16; ++s) {
        if (!(s & BWC)) continue;
        if (s & BWT) continue;
        const int t = s | BWT;
        float tr = re[s], ti = im[s];
        re[s] = re[t]; im[s] = im[t];
        re[t] = tr;    im[t] = ti;
    }
}

__device__ __forceinline__ void quantum_row(const float ang[4], const float* __restrict__ qw,
                                            const float* __restrict__ W3, const float* __restrict__ b3,
                                            float* __restrict__ o) {
    float re[16] = {}, im[16] = {};
    re[0] = 1.0f;
    ry_gate<8>(re, im, ang[0]);
    ry_gate<4>(re, im, ang[1]);
    ry_gate<2>(re, im, ang[2]);
    ry_gate<1>(re, im, ang[3]);
#pragma unroll
    for (int ll = 0; ll < 2; ++ll) {
        const float* qp = &qw[ll * 8];
        ry_gate<8>(re, im, qp[0]); rz_gate<8>(re, im, qp[1]);
        ry_gate<4>(re, im, qp[2]); rz_gate<4>(re, im, qp[3]);
        ry_gate<2>(re, im, qp[4]); rz_gate<2>(re, im, qp[5]);
        ry_gate<1>(re, im, qp[6]); rz_gate<1>(re, im, qp[7]);
        cnot_gate<8, 4>(re, im);
        cnot_gate<4, 2>(re, im);
        cnot_gate<2, 1>(re, im);
        cnot_gate<1, 8>(re, im);
    }
    float z[4] = {};
#pragma unroll
    for (int s = 0; s < 16; ++s) {
        float p = re[s] * re[s] + im[s] * im[s];
        z[0] += (s & 8) ? -p : p;
        z[1] += (s & 4) ? -p : p;
        z[2] += (s & 2) ? -p : p;
        z[3] += (s & 1) ? -p : p;
    }
#pragma unroll
    for (int c = 0; c < 10; ++c) {
        float v = b3[c];
#pragma unroll
        for (int i = 0; i < 4; ++i)
            v = fmaf(z[i], W3[c * 4 + i], v);
        o[c] = v;
    }
}

// ====== main kernel: v9 template, next-chunk loads issued AFTER barrier 1 =====
__global__ __launch_bounds__(512, 2)
void fused_qh_v11(const float* __restrict__ x,   const float* __restrict__ W1,
                  const float* __restrict__ b1,  const float* __restrict__ bn_g,
                  const float* __restrict__ bn_b,const float* __restrict__ bn_m,
                  const float* __restrict__ bn_v,const float* __restrict__ W2,
                  const float* __restrict__ b2,  const float* __restrict__ qw,
                  const float* __restrict__ W3,  const float* __restrict__ b3,
                  float* __restrict__ out)
{
    __shared__ short whi[H][SW];
    __shared__ short wlo[H][SW];
    __shared__ float hs[BM][HSS];
    __shared__ float w2s[4 * H];
    __shared__ float b1s[H], scl[H], shf[H];
    __shared__ float angs[BM][4];

    const int tid  = threadIdx.x;   // 0..511
    const int l    = tid & 63;
    const int w    = tid >> 6;      // wave 0..7 -> 16-row M stripe
    const int lr   = l & 15;
    const int lk   = l >> 4;
    const int row0 = blockIdx.x * BM;

    // prologue: small params to LDS
    if (tid < 256) w2s[tid] = W2[tid];
    if (tid < H) {
        float s = bn_g[tid] * rsqrtf(bn_v[tid] + 1e-5f);
        b1s[tid] = b1[tid];
        scl[tid] = s;
        shf[tid] = bn_b[tid] - bn_m[tid] * s;
    }

    const float4* xr4 = reinterpret_cast<const float4*>(x + (size_t)(row0 + w * 16 + lr) * D);

    // W staging mapping: f4 = tid + it*512, it=0..1
    int sn[2], sk4[2];
#pragma unroll
    for (int it = 0; it < 2; ++it) {
        int f4 = tid + it * 512;
        sn[it]  = f4 >> 4;          // 0..63
        sk4[it] = (f4 & 15) * 4;    // 0..60
    }

    f32x4 acc[4] = {{0,0,0,0},{0,0,0,0},{0,0,0,0},{0,0,0,0}};

#define LOADW(dst, c)                                                                       \
    {                                                                                       \
        _Pragma("unroll")                                                                   \
        for (int it = 0; it < 2; ++it)                                                      \
            dst[it] = *reinterpret_cast<const float4*>(&W1[(size_t)sn[it] * D + (c) * KC + sk4[it]]); \
    }

#define LOADX(dst, c)                                                  \
    {                                                                  \
        _Pragma("unroll")                                              \
        for (int i = 0; i < 4; ++i)                                    \
            dst[i] = xr4[(c) * 16 + (i >> 1) * 8 + lk * 2 + (i & 1)];  \
    }

    float4 acur[4], anxt[4], wcur[2], wnxt[2];

    LOADW(wcur, 0);
    LOADX(acur, 0);

    for (int c = 0; c < 20; ++c) {
        // ---- stage W tile for chunk c (convert + LDS write), r2-identical ----
#pragma unroll
        for (int it = 0; it < 2; ++it) {
            unsigned int lo01, lo23;
            unsigned int hi01 = pack_split(wcur[it].x, wcur[it].y, lo01);
            unsigned int hi23 = pack_split(wcur[it].z, wcur[it].w, lo23);
            uint2 hv; hv.x = hi01; hv.y = hi23;
            uint2 lv; lv.x = lo01; lv.y = lo23;
            *reinterpret_cast<uint2*>(&whi[sn[it]][sk4[it]]) = hv;
            *reinterpret_cast<uint2*>(&wlo[sn[it]][sk4[it]]) = lv;
        }
        __syncthreads();   // B1: whi/wlo(c) visible; drains prior-iter loads (long since done)

        // ---- issue next-chunk loads AFTER B1: they get the MFMA window of cover ----
        if (c + 1 < 20) {
            LOADX(anxt, c + 1);
            LOADW(wnxt, c + 1);
        }

        // ---- A fragments (hi/lo) from acur ----
        FragU ahi[2], alo[2];
#pragma unroll
        for (int h = 0; h < 2; ++h) {
            const float4 p0 = acur[h * 2 + 0];
            const float4 p1 = acur[h * 2 + 1];
            ahi[h].u[0] = pack_split(p0.x, p0.y, alo[h].u[0]);
            ahi[h].u[1] = pack_split(p0.z, p0.w, alo[h].u[1]);
            ahi[h].u[2] = pack_split(p1.x, p1.y, alo[h].u[2]);
            ahi[h].u[3] = pack_split(p1.z, p1.w, alo[h].u[3]);
        }

        // ---- MFMA ----
#pragma unroll
        for (int h = 0; h < 2; ++h)
#pragma unroll
            for (int g = 0; g < 4; ++g) {
                const bf16x8 bh = *reinterpret_cast<const bf16x8*>(&whi[g * 16 + lr][h * 32 + lk * 8]);
                const bf16x8 bl = *reinterpret_cast<const bf16x8*>(&wlo[g * 16 + lr][h * 32 + lk * 8]);
                acc[g] = __builtin_amdgcn_mfma_f32_16x16x32_bf16(ahi[h].v, bh, acc[g], 0, 0, 0);
                acc[g] = __builtin_amdgcn_mfma_f32_16x16x32_bf16(ahi[h].v, bl, acc[g], 0, 0, 0);
                acc[g] = __builtin_amdgcn_mfma_f32_16x16x32_bf16(alo[h].v, bh, acc[g], 0, 0, 0);
            }
        __syncthreads();   // B2: LDS reads done before next STOREW; drains the c+1 loads

#pragma unroll
        for (int it = 0; it < 2; ++it) wcur[it] = wnxt[it];
#pragma unroll
        for (int i = 0; i < 4; ++i) acur[i] = anxt[i];
    }
#undef LOADW
#undef LOADX

    // epilogue 1: bias -> relu -> BN -> hs (C/D: col=g*16+lr, row=lk*4+reg)
#pragma unroll
    for (int g = 0; g < 4; ++g) {
        const int cc = g * 16 + lr;
        const float b1c = b1s[cc], s = scl[cc], sh = shf[cc];
#pragma unroll
        for (int r = 0; r < 4; ++r) {
            float v = acc[g][r] + b1c;
            v = fmaxf(v, 0.0f) * s + sh;
            hs[w * 16 + lk * 4 + r][cc] = v;
        }
    }
    __syncthreads();

    // epilogue 2a: GEMM2 + double tanh, 4 threads per row (512 = 128 rows * 4)
    {
        const int row = tid >> 2, qi = tid & 3;
        float a2v = b2[qi];
#pragma unroll
        for (int k = 0; k < H; ++k)
            a2v = fmaf(hs[row][k], w2s[qi * H + k], a2v);
        float xq = tanhf(a2v);
        angs[row][qi] = tanhf(xq) * 3.14159265358979323846f;
    }
    __syncthreads();

    // epilogue 2b: quantum circuit + GEMM3, one thread per row
    if (tid < BM) {
        float ang[4] = { angs[tid][0], angs[tid][1], angs[tid][2], angs[tid][3] };
        quantum_row(ang, qw, W3, b3, &out[(size_t)(row0 + tid) * 10]);
    }
}

extern "C" void kernel_launch(void* const* d_in, const int* in_sizes, int n_in,
                              void* d_out, int out_size, void* d_ws, size_t ws_size,
                              hipStream_t stream) {
    const float* x    = (const float*)d_in[0];
    const float* W1   = (const float*)d_in[1];
    const float* b1   = (const float*)d_in[2];
    const float* bn_g = (const float*)d_in[3];
    const float* bn_b = (const float*)d_in[4];
    const float* bn_m = (const float*)d_in[5];
    const float* bn_v = (const float*)d_in[6];
    const float* W2   = (const float*)d_in[7];
    const float* b2   = (const float*)d_in[8];
    const float* qw   = (const float*)d_in[9];
    const float* W3   = (const float*)d_in[10];
    const float* b3   = (const float*)d_in[11];
    float* out = (float*)d_out;

    const int B = in_sizes[0] / D;   // 32768
    const int grid = B / BM;         // 256

    fused_qh_v11<<<grid, NT, 0, stream>>>(
        x, W1, b1, bn_g, bn_b, bn_m, bn_v, W2, b2, qw, W3, b3, out);
}

// Round 12
// 49.460 us; speedup vs baseline: 1.0188x; 1.0188x over previous
//
#include <hip/hip_runtime.h>
#include <math.h>

typedef __attribute__((ext_vector_type(8))) short bf16x8;
typedef __attribute__((ext_vector_type(4))) float f32x4;

constexpr int D   = 1280;  // input dim
constexpr int H   = 64;    // hidden
constexpr int KC  = 64;    // K chunk
constexpr int SW  = KC + 8;   // W-tile LDS row stride (verified r2 layout)
constexpr int HSS = H + 1;
constexpr int KHALF = D / 2;          // 640 = 10 chunks
constexpr int ROWS_TOTAL = 32768;

union FragU { bf16x8 v; unsigned int u[4]; };

__device__ __forceinline__ unsigned int pack_split(float f0, float f1, unsigned int& lo) {
    unsigned int u0 = __float_as_uint(f0), u1 = __float_as_uint(f1);
    unsigned int h0 = u0 & 0xFFFF0000u,    h1 = u1 & 0xFFFF0000u;
    float l0 = f0 - __uint_as_float(h0);
    float l1 = f1 - __uint_as_float(h1);
    lo = (__float_as_uint(l1) & 0xFFFF0000u) | (__float_as_uint(l0) >> 16);
    return h1 | (u0 >> 16);
}

// ---------------- quantum gates ----------------
template<int BW>
__device__ __forceinline__ void ry_gate(float re[16], float im[16], float theta) {
    float sn, cs;
    sincosf(0.5f * theta, &sn, &cs);
#pragma unroll
    for (int s0 = 0; s0 < 16; ++s0) {
        if (s0 & BW) continue;
        const int s1 = s0 | BW;
        float r0 = re[s0], i0 = im[s0], r1 = re[s1], i1 = im[s1];
        re[s0] = cs * r0 - sn * r1;  im[s0] = cs * i0 - sn * i1;
        re[s1] = sn * r0 + cs * r1;  im[s1] = sn * i0 + cs * i1;
    }
}

template<int BW>
__device__ __forceinline__ void rz_gate(float re[16], float im[16], float theta) {
    float sn, cs;
    sincosf(0.5f * theta, &sn, &cs);
#pragma unroll
    for (int s0 = 0; s0 < 16; ++s0) {
        if (s0 & BW) continue;
        const int s1 = s0 | BW;
        float r0 = re[s0], i0 = im[s0], r1 = re[s1], i1 = im[s1];
        re[s0] = cs * r0 + sn * i0;  im[s0] = cs * i0 - sn * r0;
        re[s1] = cs * r1 - sn * i1;  im[s1] = cs * i1 + sn * r1;
    }
}

template<int BWC, int BWT>
__device__ __forceinline__ void cnot_gate(float re[16], float im[16]) {
#pragma unroll
    for (int s = 0; s < 16; ++s) {
        if (!(s & BWC)) continue;
        if (s & BWT) continue;
        const int t = s | BWT;
        float tr = re[s], ti = im[s];
        re[s] = re[t]; im[s] = im[t];
        re[t] = tr;    im[t] = ti;
    }
}

__device__ __forceinline__ void quantum_row(const float ang[4], const float* __restrict__ qw,
                                            const float* __restrict__ W3, const float* __restrict__ b3,
                                            float* __restrict__ o) {
    float re[16] = {}, im[16] = {};
    re[0] = 1.0f;
    ry_gate<8>(re, im, ang[0]);
    ry_gate<4>(re, im, ang[1]);
    ry_gate<2>(re, im, ang[2]);
    ry_gate<1>(re, im, ang[3]);
#pragma unroll
    for (int ll = 0; ll < 2; ++ll) {
        const float* qp = &qw[ll * 8];
        ry_gate<8>(re, im, qp[0]); rz_gate<8>(re, im, qp[1]);
        ry_gate<4>(re, im, qp[2]); rz_gate<4>(re, im, qp[3]);
        ry_gate<2>(re, im, qp[4]); rz_gate<2>(re, im, qp[5]);
        ry_gate<1>(re, im, qp[6]); rz_gate<1>(re, im, qp[7]);
        cnot_gate<8, 4>(re, im);
        cnot_gate<4, 2>(re, im);
        cnot_gate<2, 1>(re, im);
        cnot_gate<1, 8>(re, im);
    }
    float z[4] = {};
#pragma unroll
    for (int s = 0; s < 16; ++s) {
        float p = re[s] * re[s] + im[s] * im[s];
        z[0] += (s & 8) ? -p : p;
        z[1] += (s & 4) ? -p : p;
        z[2] += (s & 2) ? -p : p;
        z[3] += (s & 1) ? -p : p;
    }
#pragma unroll
    for (int c = 0; c < 10; ++c) {
        float v = b3[c];
#pragma unroll
        for (int i = 0; i < 4; ++i)
            v = fmaf(z[i], W3[c * 4 + i], v);
        o[c] = v;
    }
}

// ============ kernel 1: K-split GEMM1 partials (r2 loop body verbatim) ========
// block bx: kh = bx&1 (K half), rb = bx>>1 (row block of 64)
__global__ __launch_bounds__(256, 4)
void gemm1_partial(const float* __restrict__ x, const float* __restrict__ W1,
                   float* __restrict__ pws)
{
    __shared__ short whi[H][SW];
    __shared__ short wlo[H][SW];

    const int tid  = threadIdx.x;
    const int l    = tid & 63;
    const int w    = tid >> 6;
    const int lr   = l & 15;
    const int lk   = l >> 4;
    const int kh   = blockIdx.x & 1;
    const int row0 = (blockIdx.x >> 1) * 64;
    const int kbase = kh * KHALF;

    const float4* xr4 = reinterpret_cast<const float4*>(x + (size_t)(row0 + w * 16 + lr) * D);

    int sn[4], sk4[4];
#pragma unroll
    for (int it = 0; it < 4; ++it) {
        int f4 = tid + it * 256;
        sn[it]  = f4 >> 4;
        sk4[it] = (f4 & 15) * 4;
    }

    f32x4 acc[4] = {{0,0,0,0},{0,0,0,0},{0,0,0,0},{0,0,0,0}};
    float4 acur[4], anxt[4], wcur[4], wnxt[4];
#pragma unroll
    for (int it = 0; it < 4; ++it)
        wcur[it] = *reinterpret_cast<const float4*>(&W1[(size_t)sn[it] * D + kbase + sk4[it]]);
#pragma unroll
    for (int h = 0; h < 2; ++h)
#pragma unroll
        for (int p = 0; p < 2; ++p)
            acur[h * 2 + p] = xr4[kbase / 4 + h * 8 + lk * 2 + p];

    for (int k0 = kbase; k0 < kbase + KHALF; k0 += KC) {
        // ---- stage W tile (convert + LDS write), r2-identical ----
#pragma unroll
        for (int it = 0; it < 4; ++it) {
            unsigned int lo01, lo23;
            unsigned int hi01 = pack_split(wcur[it].x, wcur[it].y, lo01);
            unsigned int hi23 = pack_split(wcur[it].z, wcur[it].w, lo23);
            uint2 hv; hv.x = hi01; hv.y = hi23;
            uint2 lv; lv.x = lo01; lv.y = lo23;
            *reinterpret_cast<uint2*>(&whi[sn[it]][sk4[it]]) = hv;
            *reinterpret_cast<uint2*>(&wlo[sn[it]][sk4[it]]) = lv;
        }
        if (k0 + KC < kbase + KHALF) {
            const int kn = k0 + KC;
#pragma unroll
            for (int it = 0; it < 4; ++it)
                wnxt[it] = *reinterpret_cast<const float4*>(&W1[(size_t)sn[it] * D + kn + sk4[it]]);
#pragma unroll
            for (int h = 0; h < 2; ++h)
#pragma unroll
                for (int p = 0; p < 2; ++p)
                    anxt[h * 2 + p] = xr4[kn / 4 + h * 8 + lk * 2 + p];
        }
        __syncthreads();

        FragU ahi[2], alo[2];
#pragma unroll
        for (int h = 0; h < 2; ++h) {
            const float4 p0 = acur[h * 2 + 0];
            const float4 p1 = acur[h * 2 + 1];
            ahi[h].u[0] = pack_split(p0.x, p0.y, alo[h].u[0]);
            ahi[h].u[1] = pack_split(p0.z, p0.w, alo[h].u[1]);
            ahi[h].u[2] = pack_split(p1.x, p1.y, alo[h].u[2]);
            ahi[h].u[3] = pack_split(p1.z, p1.w, alo[h].u[3]);
        }
#pragma unroll
        for (int h = 0; h < 2; ++h)
#pragma unroll
            for (int g = 0; g < 4; ++g) {
                const bf16x8 bh = *reinterpret_cast<const bf16x8*>(&whi[g * 16 + lr][h * 32 + lk * 8]);
                const bf16x8 bl = *reinterpret_cast<const bf16x8*>(&wlo[g * 16 + lr][h * 32 + lk * 8]);
                acc[g] = __builtin_amdgcn_mfma_f32_16x16x32_bf16(ahi[h].v, bh, acc[g], 0, 0, 0);
                acc[g] = __builtin_amdgcn_mfma_f32_16x16x32_bf16(ahi[h].v, bl, acc[g], 0, 0, 0);
                acc[g] = __builtin_amdgcn_mfma_f32_16x16x32_bf16(alo[h].v, bh, acc[g], 0, 0, 0);
            }
        __syncthreads();

#pragma unroll
        for (int it = 0; it < 4; ++it) { acur[it] = anxt[it]; wcur[it] = wnxt[it]; }
    }

    // store raw fp32 partials: pws[kh][row][col]  (C/D: col=g*16+lr, row=lk*4+r)
    float* base = pws + (size_t)kh * ROWS_TOTAL * H;
#pragma unroll
    for (int g = 0; g < 4; ++g) {
        const int cc = g * 16 + lr;
#pragma unroll
        for (int r = 0; r < 4; ++r) {
            const int row = row0 + w * 16 + lk * 4 + r;
            base[(size_t)row * H + cc] = acc[g][r];
        }
    }
}

// ============ kernel 2: reduce partials + BN + GEMM2 + quantum + GEMM3 ========
__global__ __launch_bounds__(256, 4)
void finish_qh(const float* __restrict__ pws,
               const float* __restrict__ b1,  const float* __restrict__ bn_g,
               const float* __restrict__ bn_b,const float* __restrict__ bn_m,
               const float* __restrict__ bn_v,const float* __restrict__ W2,
               const float* __restrict__ b2,  const float* __restrict__ qw,
               const float* __restrict__ W3,  const float* __restrict__ b3,
               float* __restrict__ out)
{
    __shared__ float hs[64][HSS];
    __shared__ float w2s[4 * H];
    __shared__ float b1s[H], scl[H], shf[H];
    __shared__ float angs[64][4];

    const int tid  = threadIdx.x;
    const int row0 = blockIdx.x * 64;

    w2s[tid] = W2[tid];
    if (tid < H) {
        float s = bn_g[tid] * rsqrtf(bn_v[tid] + 1e-5f);
        b1s[tid] = b1[tid];
        scl[tid] = s;
        shf[tid] = bn_b[tid] - bn_m[tid] * s;
    }
    __syncthreads();

    // each thread: row = tid>>2, 16 cols starting at (tid&3)*16
    {
        const int r  = tid >> 2;
        const int cb = (tid & 3) * 16;
        const float4* p0 = reinterpret_cast<const float4*>(pws + (size_t)(row0 + r) * H + cb);
        const float4* p1 = reinterpret_cast<const float4*>(pws + (size_t)ROWS_TOTAL * H + (size_t)(row0 + r) * H + cb);
#pragma unroll
        for (int j = 0; j < 4; ++j) {
            const float4 a = p0[j];
            const float4 b = p1[j];
            float vv[4] = { a.x + b.x, a.y + b.y, a.z + b.z, a.w + b.w };
#pragma unroll
            for (int q = 0; q < 4; ++q) {
                const int c = cb + j * 4 + q;
                float v = vv[q] + b1s[c];
                v = fmaxf(v, 0.0f) * scl[c] + shf[c];
                hs[r][c] = v;
            }
        }
    }
    __syncthreads();

    // GEMM2 + double tanh, 4 threads per row
    {
        const int row = tid >> 2, qi = tid & 3;
        float a2v = b2[qi];
#pragma unroll
        for (int k = 0; k < H; ++k)
            a2v = fmaf(hs[row][k], w2s[qi * H + k], a2v);
        float xq = tanhf(a2v);
        angs[row][qi] = tanhf(xq) * 3.14159265358979323846f;
    }
    __syncthreads();

    if (tid < 64) {
        float ang[4] = { angs[tid][0], angs[tid][1], angs[tid][2], angs[tid][3] };
        quantum_row(ang, qw, W3, b3, &out[(size_t)(row0 + tid) * 10]);
    }
}

// ============ fallback: verified v9 (43.5 us) =================================
constexpr int BM9 = 128;

__global__ __launch_bounds__(512, 2)
void fused_qh_v9(const float* __restrict__ x,   const float* __restrict__ W1,
                 const float* __restrict__ b1,  const float* __restrict__ bn_g,
                 const float* __restrict__ bn_b,const float* __restrict__ bn_m,
                 const float* __restrict__ bn_v,const float* __restrict__ W2,
                 const float* __restrict__ b2,  const float* __restrict__ qw,
                 const float* __restrict__ W3,  const float* __restrict__ b3,
                 float* __restrict__ out)
{
    __shared__ short whi[H][SW];
    __shared__ short wlo[H][SW];
    __shared__ float hs[BM9][HSS];
    __shared__ float w2s[4 * H];
    __shared__ float b1s[H], scl[H], shf[H];
    __shared__ float angs[BM9][4];

    const int tid  = threadIdx.x;
    const int l    = tid & 63;
    const int w    = tid >> 6;
    const int lr   = l & 15;
    const int lk   = l >> 4;
    const int row0 = blockIdx.x * BM9;

    if (tid < 256) w2s[tid] = W2[tid];
    if (tid < H) {
        float s = bn_g[tid] * rsqrtf(bn_v[tid] + 1e-5f);
        b1s[tid] = b1[tid];
        scl[tid] = s;
        shf[tid] = bn_b[tid] - bn_m[tid] * s;
    }

    const float4* xr4 = reinterpret_cast<const float4*>(x + (size_t)(row0 + w * 16 + lr) * D);

    int sn[2], sk4[2];
#pragma unroll
    for (int it = 0; it < 2; ++it) {
        int f4 = tid + it * 512;
        sn[it]  = f4 >> 4;
        sk4[it] = (f4 & 15) * 4;
    }

    f32x4 acc[4] = {{0,0,0,0},{0,0,0,0},{0,0,0,0},{0,0,0,0}};
    float4 acur[4], anxt[4], wcur[2], wnxt[2];
#pragma unroll
    for (int it = 0; it < 2; ++it)
        wcur[it] = *reinterpret_cast<const float4*>(&W1[(size_t)sn[it] * D + sk4[it]]);
#pragma unroll
    for (int h = 0; h < 2; ++h)
#pragma unroll
        for (int p = 0; p < 2; ++p)
            acur[h * 2 + p] = xr4[h * 8 + lk * 2 + p];

    for (int k0 = 0; k0 < D; k0 += KC) {
#pragma unroll
        for (int it = 0; it < 2; ++it) {
            unsigned int lo01, lo23;
            unsigned int hi01 = pack_split(wcur[it].x, wcur[it].y, lo01);
            unsigned int hi23 = pack_split(wcur[it].z, wcur[it].w, lo23);
            uint2 hv; hv.x = hi01; hv.y = hi23;
            uint2 lv; lv.x = lo01; lv.y = lo23;
            *reinterpret_cast<uint2*>(&whi[sn[it]][sk4[it]]) = hv;
            *reinterpret_cast<uint2*>(&wlo[sn[it]][sk4[it]]) = lv;
        }
        if (k0 + KC < D) {
            const int kn = k0 + KC;
#pragma unroll
            for (int it = 0; it < 2; ++it)
                wnxt[it] = *reinterpret_cast<const float4*>(&W1[(size_t)sn[it] * D + kn + sk4[it]]);
#pragma unroll
            for (int h = 0; h < 2; ++h)
#pragma unroll
                for (int p = 0; p < 2; ++p)
                    anxt[h * 2 + p] = xr4[kn / 4 + h * 8 + lk * 2 + p];
        }
        __syncthreads();

        FragU ahi[2], alo[2];
#pragma unroll
        for (int h = 0; h < 2; ++h) {
            const float4 p0 = acur[h * 2 + 0];
            const float4 p1 = acur[h * 2 + 1];
            ahi[h].u[0] = pack_split(p0.x, p0.y, alo[h].u[0]);
            ahi[h].u[1] = pack_split(p0.z, p0.w, alo[h].u[1]);
            ahi[h].u[2] = pack_split(p1.x, p1.y, alo[h].u[2]);
            ahi[h].u[3] = pack_split(p1.z, p1.w, alo[h].u[3]);
        }
#pragma unroll
        for (int h = 0; h < 2; ++h)
#pragma unroll
            for (int g = 0; g < 4; ++g) {
                const bf16x8 bh = *reinterpret_cast<const bf16x8*>(&whi[g * 16 + lr][h * 32 + lk * 8]);
                const bf16x8 bl = *reinterpret_cast<const bf16x8*>(&wlo[g * 16 + lr][h * 32 + lk * 8]);
                acc[g] = __builtin_amdgcn_mfma_f32_16x16x32_bf16(ahi[h].v, bh, acc[g], 0, 0, 0);
                acc[g] = __builtin_amdgcn_mfma_f32_16x16x32_bf16(ahi[h].v, bl, acc[g], 0, 0, 0);
                acc[g] = __builtin_amdgcn_mfma_f32_16x16x32_bf16(alo[h].v, bh, acc[g], 0, 0, 0);
            }
        __syncthreads();

#pragma unroll
        for (int it = 0; it < 2; ++it) wcur[it] = wnxt[it];
#pragma unroll
        for (int i = 0; i < 4; ++i) acur[i] = anxt[i];
    }

#pragma unroll
    for (int g = 0; g < 4; ++g) {
        const int cc = g * 16 + lr;
        const float b1c = b1s[cc], s = scl[cc], sh = shf[cc];
#pragma unroll
        for (int r = 0; r < 4; ++r) {
            float v = acc[g][r] + b1c;
            v = fmaxf(v, 0.0f) * s + sh;
            hs[w * 16 + lk * 4 + r][cc] = v;
        }
    }
    __syncthreads();

    {
        const int row = tid >> 2, qi = tid & 3;
        float a2v = b2[qi];
#pragma unroll
        for (int k = 0; k < H; ++k)
            a2v = fmaf(hs[row][k], w2s[qi * H + k], a2v);
        float xq = tanhf(a2v);
        angs[row][qi] = tanhf(xq) * 3.14159265358979323846f;
    }
    __syncthreads();

    if (tid < BM9) {
        float ang[4] = { angs[tid][0], angs[tid][1], angs[tid][2], angs[tid][3] };
        quantum_row(ang, qw, W3, b3, &out[(size_t)(row0 + tid) * 10]);
    }
}

extern "C" void kernel_launch(void* const* d_in, const int* in_sizes, int n_in,
                              void* d_out, int out_size, void* d_ws, size_t ws_size,
                              hipStream_t stream) {
    const float* x    = (const float*)d_in[0];
    const float* W1   = (const float*)d_in[1];
    const float* b1   = (const float*)d_in[2];
    const float* bn_g = (const float*)d_in[3];
    const float* bn_b = (const float*)d_in[4];
    const float* bn_m = (const float*)d_in[5];
    const float* bn_v = (const float*)d_in[6];
    const float* W2   = (const float*)d_in[7];
    const float* b2   = (const float*)d_in[8];
    const float* qw   = (const float*)d_in[9];
    const float* W3   = (const float*)d_in[10];
    const float* b3   = (const float*)d_in[11];
    float* out = (float*)d_out;

    const int B = in_sizes[0] / D;   // 32768

    const size_t need = (size_t)2 * ROWS_TOTAL * H * sizeof(float);  // 16.8 MB
    if (ws_size >= need && B == ROWS_TOTAL) {
        float* pws = (float*)d_ws;
        gemm1_partial<<<(B / 64) * 2, 256, 0, stream>>>(x, W1, pws);
        finish_qh<<<B / 64, 256, 0, stream>>>(
            pws, b1, bn_g, bn_b, bn_m, bn_v, W2, b2, qw, W3, b3, out);
    } else {
        fused_qh_v9<<<B / BM9, 512, 0, stream>>>(
            x, W1, b1, bn_g, bn_b, bn_m, bn_v, W2, b2, qw, W3, b3, out);
    }
}

// Round 14
// 43.475 us; speedup vs baseline: 1.1591x; 1.1377x over previous
//
#include <hip/hip_runtime.h>
#include <math.h>

typedef __attribute__((ext_vector_type(8))) short bf16x8;
typedef __attribute__((ext_vector_type(4))) float f32x4;

constexpr int D   = 1280;  // input dim
constexpr int H   = 64;    // hidden
constexpr int BM  = 128;   // rows per block
constexpr int NT  = 512;   // threads per block (8 waves)
constexpr int KC  = 64;    // K chunk
constexpr int SW  = KC + 8;   // W-tile LDS row stride in bf16 (verified r2 layout)
constexpr int HSS = H + 1;

union FragU { bf16x8 v; unsigned int u[4]; };

// truncation split of two f32 into packed bf16 hi pair + bf16 lo pair
__device__ __forceinline__ unsigned int pack_split(float f0, float f1, unsigned int& lo) {
    unsigned int u0 = __float_as_uint(f0), u1 = __float_as_uint(f1);
    unsigned int h0 = u0 & 0xFFFF0000u,    h1 = u1 & 0xFFFF0000u;
    float l0 = f0 - __uint_as_float(h0);
    float l1 = f1 - __uint_as_float(h1);
    lo = (__float_as_uint(l1) & 0xFFFF0000u) | (__float_as_uint(l0) >> 16);
    return h1 | (u0 >> 16);
}

// ---------------- quantum gates: 4-qubit statevector, bit weight BW ----------
template<int BW>
__device__ __forceinline__ void ry_gate(float re[16], float im[16], float theta) {
    float sn, cs;
    sincosf(0.5f * theta, &sn, &cs);
#pragma unroll
    for (int s0 = 0; s0 < 16; ++s0) {
        if (s0 & BW) continue;
        const int s1 = s0 | BW;
        float r0 = re[s0], i0 = im[s0], r1 = re[s1], i1 = im[s1];
        re[s0] = cs * r0 - sn * r1;  im[s0] = cs * i0 - sn * i1;
        re[s1] = sn * r0 + cs * r1;  im[s1] = sn * i0 + cs * i1;
    }
}

template<int BW>
__device__ __forceinline__ void rz_gate(float re[16], float im[16], float theta) {
    float sn, cs;
    sincosf(0.5f * theta, &sn, &cs);
#pragma unroll
    for (int s0 = 0; s0 < 16; ++s0) {
        if (s0 & BW) continue;
        const int s1 = s0 | BW;
        float r0 = re[s0], i0 = im[s0], r1 = re[s1], i1 = im[s1];
        re[s0] = cs * r0 + sn * i0;  im[s0] = cs * i0 - sn * r0;
        re[s1] = cs * r1 - sn * i1;  im[s1] = cs * i1 + sn * r1;
    }
}

template<int BWC, int BWT>
__device__ __forceinline__ void cnot_gate(float re[16], float im[16]) {
#pragma unroll
    for (int s = 0; s < 16; ++s) {
        if (!(s & BWC)) continue;
        if (s & BWT) continue;
        const int t = s | BWT;
        float tr = re[s], ti = im[s];
        re[s] = re[t]; im[s] = im[t];
        re[t] = tr;    im[t] = ti;
    }
}

__device__ __forceinline__ void quantum_row(const float ang[4], const float* __restrict__ qw,
                                            const float* __restrict__ W3, const float* __restrict__ b3,
                                            float* __restrict__ o) {
    float re[16] = {}, im[16] = {};
    re[0] = 1.0f;
    ry_gate<8>(re, im, ang[0]);
    ry_gate<4>(re, im, ang[1]);
    ry_gate<2>(re, im, ang[2]);
    ry_gate<1>(re, im, ang[3]);
#pragma unroll
    for (int ll = 0; ll < 2; ++ll) {
        const float* qp = &qw[ll * 8];
        ry_gate<8>(re, im, qp[0]); rz_gate<8>(re, im, qp[1]);
        ry_gate<4>(re, im, qp[2]); rz_gate<4>(re, im, qp[3]);
        ry_gate<2>(re, im, qp[4]); rz_gate<2>(re, im, qp[5]);
        ry_gate<1>(re, im, qp[6]); rz_gate<1>(re, im, qp[7]);
        cnot_gate<8, 4>(re, im);
        cnot_gate<4, 2>(re, im);
        cnot_gate<2, 1>(re, im);
        cnot_gate<1, 8>(re, im);
    }
    float z[4] = {};
#pragma unroll
    for (int s = 0; s < 16; ++s) {
        float p = re[s] * re[s] + im[s] * im[s];
        z[0] += (s & 8) ? -p : p;
        z[1] += (s & 4) ? -p : p;
        z[2] += (s & 2) ? -p : p;
        z[3] += (s & 1) ? -p : p;
    }
#pragma unroll
    for (int c = 0; c < 10; ++c) {
        float v = b3[c];
#pragma unroll
        for (int i = 0; i < 4; ++i)
            v = fmaf(z[i], W3[c * 4 + i], v);
        o[c] = v;
    }
}

// ====== main kernel: verified v9 (round 9, 43.48 us) ==========================
__global__ __launch_bounds__(512, 2)
void fused_qh_v9(const float* __restrict__ x,   const float* __restrict__ W1,
                 const float* __restrict__ b1,  const float* __restrict__ bn_g,
                 const float* __restrict__ bn_b,const float* __restrict__ bn_m,
                 const float* __restrict__ bn_v,const float* __restrict__ W2,
                 const float* __restrict__ b2,  const float* __restrict__ qw,
                 const float* __restrict__ W3,  const float* __restrict__ b3,
                 float* __restrict__ out)
{
    __shared__ short whi[H][SW];
    __shared__ short wlo[H][SW];
    __shared__ float hs[BM][HSS];
    __shared__ float w2s[4 * H];
    __shared__ float b1s[H], scl[H], shf[H];
    __shared__ float angs[BM][4];

    const int tid  = threadIdx.x;   // 0..511
    const int l    = tid & 63;
    const int w    = tid >> 6;      // wave 0..7 -> 16-row M stripe
    const int lr   = l & 15;
    const int lk   = l >> 4;
    const int row0 = blockIdx.x * BM;

    // prologue: small params to LDS
    if (tid < 256) w2s[tid] = W2[tid];
    if (tid < H) {
        float s = bn_g[tid] * rsqrtf(bn_v[tid] + 1e-5f);
        b1s[tid] = b1[tid];
        scl[tid] = s;
        shf[tid] = bn_b[tid] - bn_m[tid] * s;
    }

    const float4* xr4 = reinterpret_cast<const float4*>(x + (size_t)(row0 + w * 16 + lr) * D);

    // W staging mapping (r2 formula, 512 threads): f4 = tid + it*512, it=0..1
    int sn[2], sk4[2];
#pragma unroll
    for (int it = 0; it < 2; ++it) {
        int f4 = tid + it * 512;
        sn[it]  = f4 >> 4;          // 0..63
        sk4[it] = (f4 & 15) * 4;    // 0..60
    }

    f32x4 acc[4] = {{0,0,0,0},{0,0,0,0},{0,0,0,0},{0,0,0,0}};
    float4 acur[4], anxt[4], wcur[2], wnxt[2];
#pragma unroll
    for (int it = 0; it < 2; ++it)
        wcur[it] = *reinterpret_cast<const float4*>(&W1[(size_t)sn[it] * D + sk4[it]]);
#pragma unroll
    for (int h = 0; h < 2; ++h)
#pragma unroll
        for (int p = 0; p < 2; ++p)
            acur[h * 2 + p] = xr4[h * 8 + lk * 2 + p];

    for (int k0 = 0; k0 < D; k0 += KC) {
        // ---- stage W tile (convert + LDS write), r2-identical pattern ----
#pragma unroll
        for (int it = 0; it < 2; ++it) {
            unsigned int lo01, lo23;
            unsigned int hi01 = pack_split(wcur[it].x, wcur[it].y, lo01);
            unsigned int hi23 = pack_split(wcur[it].z, wcur[it].w, lo23);
            uint2 hv; hv.x = hi01; hv.y = hi23;
            uint2 lv; lv.x = lo01; lv.y = lo23;
            *reinterpret_cast<uint2*>(&whi[sn[it]][sk4[it]]) = hv;
            *reinterpret_cast<uint2*>(&wlo[sn[it]][sk4[it]]) = lv;
        }
        // ---- prefetch next chunk into registers ----
        if (k0 + KC < D) {
            const int kn = k0 + KC;
#pragma unroll
            for (int it = 0; it < 2; ++it)
                wnxt[it] = *reinterpret_cast<const float4*>(&W1[(size_t)sn[it] * D + kn + sk4[it]]);
#pragma unroll
            for (int h = 0; h < 2; ++h)
#pragma unroll
                for (int p = 0; p < 2; ++p)
                    anxt[h * 2 + p] = xr4[kn / 4 + h * 8 + lk * 2 + p];
        }
        __syncthreads();

        // ---- A fragments (hi/lo) ----
        FragU ahi[2], alo[2];
#pragma unroll
        for (int h = 0; h < 2; ++h) {
            const float4 p0 = acur[h * 2 + 0];
            const float4 p1 = acur[h * 2 + 1];
            ahi[h].u[0] = pack_split(p0.x, p0.y, alo[h].u[0]);
            ahi[h].u[1] = pack_split(p0.z, p0.w, alo[h].u[1]);
            ahi[h].u[2] = pack_split(p1.x, p1.y, alo[h].u[2]);
            ahi[h].u[3] = pack_split(p1.z, p1.w, alo[h].u[3]);
        }

        // ---- MFMA: full 64-col tile per wave (r2-identical) ----
#pragma unroll
        for (int h = 0; h < 2; ++h)
#pragma unroll
            for (int g = 0; g < 4; ++g) {
                const bf16x8 bh = *reinterpret_cast<const bf16x8*>(&whi[g * 16 + lr][h * 32 + lk * 8]);
                const bf16x8 bl = *reinterpret_cast<const bf16x8*>(&wlo[g * 16 + lr][h * 32 + lk * 8]);
                acc[g] = __builtin_amdgcn_mfma_f32_16x16x32_bf16(ahi[h].v, bh, acc[g], 0, 0, 0);
                acc[g] = __builtin_amdgcn_mfma_f32_16x16x32_bf16(ahi[h].v, bl, acc[g], 0, 0, 0);
                acc[g] = __builtin_amdgcn_mfma_f32_16x16x32_bf16(alo[h].v, bh, acc[g], 0, 0, 0);
            }
        __syncthreads();

#pragma unroll
        for (int it = 0; it < 2; ++it) wcur[it] = wnxt[it];
#pragma unroll
        for (int i = 0; i < 4; ++i) acur[i] = anxt[i];
    }

    // epilogue 1: bias -> relu -> BN -> hs (C/D: col=g*16+lr, row=lk*4+reg)
#pragma unroll
    for (int g = 0; g < 4; ++g) {
        const int cc = g * 16 + lr;
        const float b1c = b1s[cc], s = scl[cc], sh = shf[cc];
#pragma unroll
        for (int r = 0; r < 4; ++r) {
            float v = acc[g][r] + b1c;
            v = fmaxf(v, 0.0f) * s + sh;
            hs[w * 16 + lk * 4 + r][cc] = v;
        }
    }
    __syncthreads();

    // epilogue 2a: GEMM2 + double tanh, 4 threads per row (512 = 128 rows * 4)
    {
        const int row = tid >> 2, qi = tid & 3;
        float a2v = b2[qi];
#pragma unroll
        for (int k = 0; k < H; ++k)
            a2v = fmaf(hs[row][k], w2s[qi * H + k], a2v);
        float xq = tanhf(a2v);
        angs[row][qi] = tanhf(xq) * 3.14159265358979323846f;
    }
    __syncthreads();

    // epilogue 2b: quantum circuit + GEMM3, one thread per row
    if (tid < BM) {
        float ang[4] = { angs[tid][0], angs[tid][1], angs[tid][2], angs[tid][3] };
        quantum_row(ang, qw, W3, b3, &out[(size_t)(row0 + tid) * 10]);
    }
}

extern "C" void kernel_launch(void* const* d_in, const int* in_sizes, int n_in,
                              void* d_out, int out_size, void* d_ws, size_t ws_size,
                              hipStream_t stream) {
    const float* x    = (const float*)d_in[0];
    const float* W1   = (const float*)d_in[1];
    const float* b1   = (const float*)d_in[2];
    const float* bn_g = (const float*)d_in[3];
    const float* bn_b = (const float*)d_in[4];
    const float* bn_m = (const float*)d_in[5];
    const float* bn_v = (const float*)d_in[6];
    const float* W2   = (const float*)d_in[7];
    const float* b2   = (const float*)d_in[8];
    const float* qw   = (const float*)d_in[9];
    const float* W3   = (const float*)d_in[10];
    const float* b3   = (const float*)d_in[11];
    float* out = (float*)d_out;

    const int B = in_sizes[0] / D;   // 32768
    const int grid = B / BM;         // 256

    fused_qh_v9<<<grid, NT, 0, stream>>>(
        x, W1, b1, bn_g, bn_b, bn_m, bn_v, W2, b2, qw, W3, b3, out);
}